// Round 15
// baseline (272.740 us; speedup 1.0000x reference)
//
#include <hip/hip_runtime.h>
#include <hip/hip_fp16.h>

typedef float f32x4 __attribute__((ext_vector_type(4)));
typedef __bf16 bf16x8 __attribute__((ext_vector_type(8)));
typedef unsigned int u32x4 __attribute__((ext_vector_type(4)));
typedef __attribute__((address_space(3))) const void* lds_cp;

#define BB_ 8
#define TT_ 4096
#define DD_ 1024
#define MM_ (BB_*TT_)   // 32768
#define KK_ DD_         // 1024

#define NCH 64
#define LCH (TT_/NCH)   // 64

static __device__ __forceinline__ unsigned short f2bf_rn(float f) {
  unsigned int u = __float_as_uint(f);
  u += 0x7FFFu + ((u >> 16) & 1u);
  return (unsigned short)(u >> 16);
}

// ------------- merged conversion: X (straight) + W (interleaved) ----------
// items 0..NX4-1: X float4 -> bf16x4 straight copy.
// items NX4..NX4+NW4-1: W float4 -> Wcat row e = (D>>5)*64 + mtx*32 + (D&31)
// (a wave's j and j+2 fragments then give (k, th) for the SAME channel).
__global__ void cvt_inputs(const float4* __restrict__ X4,
                           const float4* __restrict__ Wz4,
                           const float4* __restrict__ Wh4,
                           ushort4* __restrict__ Xb4,
                           ushort4* __restrict__ Wcat) {
  const int NX4 = MM_ * (DD_ / 4);               // 8388608
  const int NW4 = 2 * DD_ * (DD_ / 4);           // 524288
  int stride = gridDim.x * blockDim.x;
  for (int i = blockIdx.x * blockDim.x + threadIdx.x; i < NX4 + NW4;
       i += stride) {
    if (i < NX4) {
      float4 v = X4[i];
      ushort4 o;
      o.x = f2bf_rn(v.x); o.y = f2bf_rn(v.y);
      o.z = f2bf_rn(v.z); o.w = f2bf_rn(v.w);
      Xb4[i] = o;
    } else {
      int flat = i - NX4;                        // 0..524287
      int mtx = flat >> 18;                      // 0 = Wz, 1 = Wh
      int j = flat & 262143;
      float4 v = (mtx ? Wh4 : Wz4)[j];
      int D = j >> 8;                            // source row 0..1023
      int kq = j & 255;                          // float4 col
      int e = ((D >> 5) << 6) + (mtx << 5) + (D & 31);
      ushort4 o;
      o.x = f2bf_rn(v.x); o.y = f2bf_rn(v.y);
      o.z = f2bf_rn(v.z); o.w = f2bf_rn(v.w);
      Wcat[(size_t)e * 256 + kq] = o;
    }
  }
}

// -- GEMM: 256^2, BK=64, asm-pipelined reads, 1 barrier/phase, cnt waits ---
__device__ __forceinline__ void gload_lds16(const void* g, void* l) {
  __builtin_amdgcn_global_load_lds(
      (const __attribute__((address_space(1))) void*)g,
      (__attribute__((address_space(3))) void*)l, 16, 0, 0);
}

#define STA(q, nb_, kkh) gload_lds16(pXa + (q) * 65536 + (kkh), (nb_) + (q) * 8192 + wofs)
#define STB(q, nb_, kkh) gload_lds16(pWb + (q) * 65536 + (kkh), (nb_) + 32768 + (q) * 8192 + wofs)

// inline-asm ds_read_b128 (we own the waitcnt for these, not the compiler)
#define DSR(dst, gp) \
  asm volatile("ds_read_b128 %0, %1" : "=&v"(dst) : "v"((lds_cp)(gp)))

// A-fragment quad (mh, k-slot byte sk_) from buffer base_
#define RD_A(SET, base_, mh, sk_) do {                                      \
    DSR(SET[0], (base_) + rA7 + (mh) * 8192 + 0 * 2048 + (sk_));            \
    DSR(SET[1], (base_) + rA7 + (mh) * 8192 + 1 * 2048 + (sk_));            \
    DSR(SET[2], (base_) + rA7 + (mh) * 8192 + 2 * 2048 + (sk_));            \
    DSR(SET[3], (base_) + rA7 + (mh) * 8192 + 3 * 2048 + (sk_));            \
  } while (0)
// B-fragment quad (k-slot byte sk_) from buffer base_
#define RD_B(SET, base_, sk_) do {                                          \
    DSR(SET[0], (base_) + rB7 + 0 * 2048 + (sk_));                          \
    DSR(SET[1], (base_) + rB7 + 1 * 2048 + (sk_));                          \
    DSR(SET[2], (base_) + rB7 + 2 * 2048 + (sk_));                          \
    DSR(SET[3], (base_) + rB7 + 3 * 2048 + (sk_));                          \
  } while (0)

#define BC(x) __builtin_bit_cast(bf16x8, x)
#define MFMA16(ASET, BSET, mh) do {                                         \
    __builtin_amdgcn_s_setprio(1);                                          \
    _Pragma("unroll")                                                       \
    for (int ii = 0; ii < 4; ++ii)                                          \
      _Pragma("unroll")                                                     \
      for (int j = 0; j < 4; ++j)                                           \
        acc[(mh) * 4 + ii][j] = __builtin_amdgcn_mfma_f32_16x16x32_bf16(    \
            BC(ASET[ii]), BC(BSET[j]), acc[(mh) * 4 + ii][j], 0, 0, 0);     \
    __builtin_amdgcn_s_setprio(0);                                          \
  } while (0)

#define BAR() do { __builtin_amdgcn_s_barrier();                            \
                   __builtin_amdgcn_sched_barrier(0); } while (0)
#define SB()  __builtin_amdgcn_sched_barrier(0)
#define LGKM(n) do { asm volatile("s_waitcnt lgkmcnt(" #n ")" ::: "memory");\
                     SB(); } while (0)
#define VMW(n) asm volatile("s_waitcnt vmcnt(" #n ")" ::: "memory")

__global__ __launch_bounds__(512, 2) void gemm_fused(
    const unsigned short* __restrict__ Xb,   // [M][K] bf16 bits
    const unsigned short* __restrict__ Wb,   // [2048][K] bf16 bits (Wcat)
    const float* __restrict__ bz, const float* __restrict__ bh,
    unsigned int* __restrict__ ZG,           // [M][1024] packed (z | g<<16)
    float* __restrict__ Pp, float* __restrict__ Qq)   // [B][64][1024]
{
  extern __shared__ __align__(16) char smem[];   // 2 x (A 32KB + B 32KB)
  const int tid  = threadIdx.x;
  const int wave = tid >> 6;
  const int lane = tid & 63;
  const int wm = wave >> 2, wn = wave & 3;       // 2M x 4N waves
  const int fr = lane & 15, kg = lane >> 4;

  // XCD-bijective swizzle (1024 % 8 == 0); N-fastest within each XCD strip.
  int swz = (blockIdx.x & 7) * 128 + (blockIdx.x >> 3);
  const int m0 = (swz >> 3) * 256;
  const int e0 = (swz & 7) * 256;                // Wcat col-tile base

  // staging per-thread constants (pre-swizzled global source)
  const int arow = tid >> 3;                         // 0..63 row within round
  const int aslx = ((tid & 7) ^ (arow & 7)) * 8;     // swizzled 16B-chunk
  const unsigned short* pXa = Xb + (size_t)(m0 + arow) * KK_ + aslx;
  const unsigned short* pWb = Wb + (size_t)(e0 + arow) * KK_ + aslx;
  const int wofs = wave * 1024;                      // wave slice (bytes)

  // ds_read per-thread constants (swizzled read side)
  const int rA7 = (wm * 128 + fr) * 128;             // A row byte offset
  const int rB7 = 32768 + (wn * 64 + fr) * 128;      // B row byte offset
  const int fx = fr & 7;
  const int sk0 = (kg ^ fx) * 16;                    // k-half 0 slot byte
  const int sk1 = sk0 ^ 64;                          // k-half 1 slot byte

  f32x4 acc[8][4];
  #pragma unroll
  for (int i = 0; i < 8; i++)
    #pragma unroll
    for (int j = 0; j < 4; j++)
      acc[i][j] = (f32x4){0.f, 0.f, 0.f, 0.f};
  u32x4 aP[4], aQ[4], bk0[4], bk1[4];   // fragment reg sets (static idx only)

  // prologue: stage K-tile 0 into buf0; first-needed 6 rounds drained
  STA(0, smem, 0); STA(2, smem, 0); STB(0, smem, 0);
  STB(1, smem, 0); STB(2, smem, 0); STB(3, smem, 0);
  STA(1, smem, 0); STA(3, smem, 0);
  VMW(2);                                   // A0,A2,B0..B3 landed
  __builtin_amdgcn_s_barrier();
  SB();
  RD_A(aP, smem, 0, sk0);                   // (mh0,kh0) of tile 0
  RD_B(bk0, smem, sk0);

  // loop: 4 phases/tile, ONE barrier/phase, reads pipelined one phase ahead.
  // Wait ledger (per wave, outstanding <= 8 vmem / 8 ds):
  //  ph0: VMW(0) drains A1',A3' (issued ph2 prev) before reading them.
  //  ph3: VMW(2) drains A0',A2',B0'..B3' (issued ph0/ph1) before reading nb.
  //  LGKM(n) leaves the n just-issued reads outstanding, drains the set the
  //  imminent MFMA consumes (issued one phase earlier).
  #pragma unroll 1
  for (int t = 0; t < 15; ++t) {
    const char* cb = smem + ((t & 1) << 16);
    char* nb = smem + (((t + 1) & 1) << 16);
    const int kn = (t + 1) * 64;                     // half-elem K offset
    // ph0: MFMA(mh0,kh0) on aP/bk0; read aQ=(mh1,kh0); stage A0',A2',B0'
    VMW(0);
    BAR();
    RD_A(aQ, cb, 1, sk0);
    STA(0, nb, kn); STA(2, nb, kn); STB(0, nb, kn);
    LGKM(4);
    MFMA16(aP, bk0, 0);
    // ph1: MFMA(mh1,kh0) on aQ/bk0; read aP=(mh0,kh1)+bk1; stage B1'..B3'
    BAR();
    RD_A(aP, cb, 0, sk1);
    RD_B(bk1, cb, sk1);
    STB(1, nb, kn); STB(2, nb, kn); STB(3, nb, kn);
    LGKM(8);
    MFMA16(aQ, bk0, 1);
    // ph2: MFMA(mh0,kh1) on aP/bk1; read aQ=(mh1,kh1); stage A1',A3'
    BAR();
    RD_A(aQ, cb, 1, sk1);
    STA(1, nb, kn); STA(3, nb, kn);
    LGKM(4);
    MFMA16(aP, bk1, 0);
    // ph3: MFMA(mh1,kh1) on aQ/bk1; read next tile's aP+bk0 from nb
    VMW(2);
    BAR();
    RD_A(aP, nb, 0, sk0);
    RD_B(bk0, nb, sk0);
    LGKM(8);
    MFMA16(aQ, bk1, 1);
  }
  {                                                  // peeled tile 15 (buf1)
    const char* cb = smem + 65536;
    VMW(0);
    BAR();
    RD_A(aQ, cb, 1, sk0);
    LGKM(4);  MFMA16(aP, bk0, 0);
    BAR();
    RD_A(aP, cb, 0, sk1);
    RD_B(bk1, cb, sk1);
    LGKM(8);  MFMA16(aQ, bk0, 1);
    BAR();
    RD_A(aQ, cb, 1, sk1);
    LGKM(4);  MFMA16(aP, bk1, 0);
    BAR();
    LGKM(0);  MFMA16(aQ, bk1, 1);
  }
  __syncthreads();                          // all LDS reads done -> reuse smem

  // ===== epilogue: activation + in-register chunk scan + packed ZG ========
  // lane's channel (j = 0,1): d = dw0 + j*16 + fr ; k = acc[a][j], th = acc[a][j+2]
  const int dw0 = (swz & 7) * 128 + wn * 32;         // wave's 32 channels
  const int t0 = m0 & 4095;                          // t base within batch
  const int bidx = m0 >> 12;                         // batch

  float bzv[2], bhv[2];
  #pragma unroll
  for (int j = 0; j < 2; ++j) {
    bzv[j] = bz[dw0 + j * 16 + fr];
    bhv[j] = bh[dw0 + j * 16 + fr];
  }

  unsigned int* ew = (unsigned int*)(smem + wave * 9216);  // [64 t][36 dw]
  const int sub = lane & 7, rowr = lane >> 3;

  #pragma unroll
  for (int p = 0; p < 2; ++p) {                      // two 64-t chunks
    float PP[2] = {1.f, 1.f}, QQ[2] = {0.f, 0.f};
    #pragma unroll
    for (int ii = 0; ii < 4; ++ii) {                 // ascending t blocks of 16
      #pragma unroll
      for (int j = 0; j < 2; ++j) {
        float segP = 1.f, segQ = 0.f;
        #pragma unroll
        for (int r = 0; r < 4; ++r) {                // 4 consecutive t
          float kz = acc[p * 4 + ii][j][r] + bzv[j];
          float th = acc[p * 4 + ii][j + 2][r] + bhv[j];
          float z = 1.0f / (1.0f + __expf(-kz));
          float g = (th >= 0.0f) ? (th + 0.5f)
                                 : (1.0f / (1.0f + __expf(-th)));
          unsigned int pk =
              (unsigned int)__half_as_ushort(__float2half(z)) |
              ((unsigned int)__half_as_ushort(__float2half(g)) << 16);
          ew[(ii * 16 + kg * 4 + r) * 36 + j * 16 + fr] = pk;
          float aa = 1.f - z;
          segP *= aa;
          segQ = fmaf(aa, segQ, z * g);
        }
        // suffix-combine across kg (t-ordered: kg ascending = later)
        float p1 = __shfl_down(segP, 16), q1 = __shfl_down(segQ, 16);
        segQ = fmaf(p1, segQ, q1); segP *= p1;
        float p2 = __shfl_down(segP, 32), q2 = __shfl_down(segQ, 32);
        segQ = fmaf(p2, segQ, q2); segP *= p2;
        QQ[j] = fmaf(segP, QQ[j], segQ);
        PP[j] *= segP;
      }
    }
    if (kg == 0) {                                   // one lane per (d, chunk)
      const int cg = (t0 >> 6) + wm * 2 + p;
      #pragma unroll
      for (int j = 0; j < 2; ++j) {
        size_t po = ((size_t)bidx * NCH + cg) * DD_ + dw0 + j * 16 + fr;
        Pp[po] = PP[j];
        Qq[po] = QQ[j];
      }
    }
    // coalesced ZG store via LDS readback (wave-synchronous, own region)
    #pragma unroll
    for (int q = 0; q < 8; ++q) {
      int rl = q * 8 + rowr;
      uint4 v = *reinterpret_cast<const uint4*>(&ew[rl * 36 + sub * 4]);
      size_t rg = (size_t)(m0 + wm * 128 + p * 64 + rl);
      *reinterpret_cast<uint4*>(&ZG[rg * DD_ + dw0 + sub * 4]) = v;
    }
  }
}

// -------- scan apply (fused combine): h-in fold + apply + write out -------
__global__ __launch_bounds__(256) void scan_apply(
    const uint4* __restrict__ ZG,
    const float4* __restrict__ P, const float4* __restrict__ Q,
    float4* __restrict__ out) {
  const int d4 = threadIdx.x;
  const int c  = blockIdx.x;
  const int b  = blockIdx.y;
  // fold chunks 0..c-1 (same order as the old scan_combine -> bitwise equal)
  float4 h = make_float4(0.f, 0.f, 0.f, 0.f);
  for (int cc = 0; cc < c; ++cc) {
    size_t o = ((size_t)b * NCH + cc) * (DD_ / 4) + d4;
    float4 p = P[o], q = Q[o];
    h.x = fmaf(p.x, h.x, q.x);
    h.y = fmaf(p.y, h.y, q.y);
    h.z = fmaf(p.z, h.z, q.z);
    h.w = fmaf(p.w, h.w, q.w);
  }
  size_t base = ((size_t)b * TT_ + (size_t)c * LCH) * (DD_ / 4) + d4;
  for (int t = 0; t < LCH; ++t) {
    uint4 w = ZG[base + (size_t)t * (DD_ / 4)];
    float z, g, a;
    z = __half2float(__ushort_as_half((unsigned short)(w.x & 0xffff)));
    g = __half2float(__ushort_as_half((unsigned short)(w.x >> 16)));
    a = 1.f - z; h.x = fmaf(a, h.x, z * g);
    z = __half2float(__ushort_as_half((unsigned short)(w.y & 0xffff)));
    g = __half2float(__ushort_as_half((unsigned short)(w.y >> 16)));
    a = 1.f - z; h.y = fmaf(a, h.y, z * g);
    z = __half2float(__ushort_as_half((unsigned short)(w.z & 0xffff)));
    g = __half2float(__ushort_as_half((unsigned short)(w.z >> 16)));
    a = 1.f - z; h.z = fmaf(a, h.z, z * g);
    z = __half2float(__ushort_as_half((unsigned short)(w.w & 0xffff)));
    g = __half2float(__ushort_as_half((unsigned short)(w.w >> 16)));
    a = 1.f - z; h.w = fmaf(a, h.w, z * g);
    out[base + (size_t)t * (DD_ / 4)] = h;
  }
}

extern "C" void kernel_launch(void* const* d_in, const int* in_sizes, int n_in,
                              void* d_out, int out_size, void* d_ws, size_t ws_size,
                              hipStream_t stream) {
  const float* X  = (const float*)d_in[0];  // [8,4096,1024]
  const float* Wz = (const float*)d_in[1];  // [1024,1024]
  const float* bz = (const float*)d_in[2];
  const float* Wh = (const float*)d_in[3];
  const float* bh = (const float*)d_in[4];
  float* out = (float*)d_out;

  const size_t szXb = (size_t)MM_ * DD_ * 2;      // 64 MiB  bf16 X
  const size_t szWb = (size_t)2 * DD_ * DD_ * 2;  //  4 MiB  bf16 Wcat
  const size_t szZG = (size_t)MM_ * DD_ * 4;      // 128 MiB packed z,g
  const size_t szPQ = (size_t)BB_ * NCH * DD_ * 4;//  2 MiB  each

  char* ws = (char*)d_ws;
  unsigned short *Xb, *Wb;
  const size_t needA = szXb + szWb + szZG + 2 * szPQ;
  if (ws_size >= needA) {
    Xb = (unsigned short*)ws;              ws += szXb;
    Wb = (unsigned short*)ws;              ws += szWb;
  } else {
    // fallback: stage X/W inside d_out (dead until scan_apply), rest in ws
    Xb = (unsigned short*)d_out;
    Wb = (unsigned short*)((char*)d_out + szXb);
  }
  unsigned int* ZG = (unsigned int*)ws;  ws += szZG;
  float* P = (float*)ws;  ws += szPQ;
  float* Q = (float*)ws;

  // 1) single merged conversion launch: X -> bf16, W -> interleaved Wcat
  cvt_inputs<<<2048, 256, 0, stream>>>((const float4*)X, (const float4*)Wz,
                                       (const float4*)Wh, (ushort4*)Xb,
                                       (ushort4*)Wb);
  // 2) fused GEMM -> packed ZG + per-chunk P,Q  (M=32768, N=2048, K=1024)
  gemm_fused<<<(MM_ / 256) * ((2 * DD_) / 256), 512, 131072, stream>>>(
      Xb, Wb, bz, bh, ZG, P, Q);

  // 3) fused combine+apply (h-in fold per block, bitwise same as before)
  scan_apply<<<dim3(NCH, BB_), 256, 0, stream>>>((const uint4*)ZG,
                                                 (const float4*)P,
                                                 (const float4*)Q,
                                                 (float4*)out);
}

// Round 16
// 259.579 us; speedup vs baseline: 1.0507x; 1.0507x over previous
//
#include <hip/hip_runtime.h>
#include <hip/hip_fp16.h>

typedef float f32x4 __attribute__((ext_vector_type(4)));
typedef __bf16 bf16x8 __attribute__((ext_vector_type(8)));
typedef unsigned int u32x4 __attribute__((ext_vector_type(4)));
typedef __attribute__((address_space(3))) const void* lds_cp;

#define BB_ 8
#define TT_ 4096
#define DD_ 1024
#define MM_ (BB_*TT_)   // 32768
#define KK_ DD_         // 1024

#define NCH 64
#define LCH (TT_/NCH)   // 64

static __device__ __forceinline__ unsigned short f2bf_rn(float f) {
  unsigned int u = __float_as_uint(f);
  u += 0x7FFFu + ((u >> 16) & 1u);
  return (unsigned short)(u >> 16);
}

// ------------- merged conversion: X (straight) + W (interleaved) ----------
// items 0..NX4-1: X float4 -> bf16x4 straight copy.
// items NX4..NX4+NW4-1: W float4 -> Wcat row e = (D>>5)*64 + mtx*32 + (D&31)
// (a wave's j and j+2 fragments then give (k, th) for the SAME channel).
__global__ void cvt_inputs(const float4* __restrict__ X4,
                           const float4* __restrict__ Wz4,
                           const float4* __restrict__ Wh4,
                           ushort4* __restrict__ Xb4,
                           ushort4* __restrict__ Wcat) {
  const int NX4 = MM_ * (DD_ / 4);               // 8388608
  const int NW4 = 2 * DD_ * (DD_ / 4);           // 524288
  int stride = gridDim.x * blockDim.x;
  for (int i = blockIdx.x * blockDim.x + threadIdx.x; i < NX4 + NW4;
       i += stride) {
    if (i < NX4) {
      float4 v = X4[i];
      ushort4 o;
      o.x = f2bf_rn(v.x); o.y = f2bf_rn(v.y);
      o.z = f2bf_rn(v.z); o.w = f2bf_rn(v.w);
      Xb4[i] = o;
    } else {
      int flat = i - NX4;                        // 0..524287
      int mtx = flat >> 18;                      // 0 = Wz, 1 = Wh
      int j = flat & 262143;
      float4 v = (mtx ? Wh4 : Wz4)[j];
      int D = j >> 8;                            // source row 0..1023
      int kq = j & 255;                          // float4 col
      int e = ((D >> 5) << 6) + (mtx << 5) + (D & 31);
      ushort4 o;
      o.x = f2bf_rn(v.x); o.y = f2bf_rn(v.y);
      o.z = f2bf_rn(v.z); o.w = f2bf_rn(v.w);
      Wcat[(size_t)e * 256 + kq] = o;
    }
  }
}

// -- GEMM: 256^2, BK=64, asm-pipelined reads, 1 barrier/phase, cnt waits ---
__device__ __forceinline__ void gload_lds16(const void* g, void* l) {
  __builtin_amdgcn_global_load_lds(
      (const __attribute__((address_space(1))) void*)g,
      (__attribute__((address_space(3))) void*)l, 16, 0, 0);
}

#define STA(q, nb_, kkh) gload_lds16(pXa + (q) * 65536 + (kkh), (nb_) + (q) * 8192 + wofs)
#define STB(q, nb_, kkh) gload_lds16(pWb + (q) * 65536 + (kkh), (nb_) + 32768 + (q) * 8192 + wofs)

// inline-asm ds_read_b128 (we own the waitcnt for these, not the compiler)
#define DSR(dst, gp) \
  asm volatile("ds_read_b128 %0, %1" : "=&v"(dst) : "v"((lds_cp)(gp)))

// A-fragment quad (mh, k-slot byte sk_) from buffer base_
#define RD_A(SET, base_, mh, sk_) do {                                      \
    DSR(SET[0], (base_) + rA7 + (mh) * 8192 + 0 * 2048 + (sk_));            \
    DSR(SET[1], (base_) + rA7 + (mh) * 8192 + 1 * 2048 + (sk_));            \
    DSR(SET[2], (base_) + rA7 + (mh) * 8192 + 2 * 2048 + (sk_));            \
    DSR(SET[3], (base_) + rA7 + (mh) * 8192 + 3 * 2048 + (sk_));            \
  } while (0)
// B-fragment quad (k-slot byte sk_) from buffer base_
#define RD_B(SET, base_, sk_) do {                                          \
    DSR(SET[0], (base_) + rB7 + 0 * 2048 + (sk_));                          \
    DSR(SET[1], (base_) + rB7 + 1 * 2048 + (sk_));                          \
    DSR(SET[2], (base_) + rB7 + 2 * 2048 + (sk_));                          \
    DSR(SET[3], (base_) + rB7 + 3 * 2048 + (sk_));                          \
  } while (0)

#define BC(x) __builtin_bit_cast(bf16x8, x)
#define MFMA16(ASET, BSET, mh) do {                                         \
    __builtin_amdgcn_s_setprio(1);                                          \
    _Pragma("unroll")                                                       \
    for (int ii = 0; ii < 4; ++ii)                                          \
      _Pragma("unroll")                                                     \
      for (int j = 0; j < 4; ++j)                                           \
        acc[(mh) * 4 + ii][j] = __builtin_amdgcn_mfma_f32_16x16x32_bf16(    \
            BC(ASET[ii]), BC(BSET[j]), acc[(mh) * 4 + ii][j], 0, 0, 0);     \
    __builtin_amdgcn_s_setprio(0);                                          \
  } while (0)

#define BAR() do { __builtin_amdgcn_s_barrier();                            \
                   __builtin_amdgcn_sched_barrier(0); } while (0)
#define SB()  __builtin_amdgcn_sched_barrier(0)
#define LGKM(n) do { asm volatile("s_waitcnt lgkmcnt(" #n ")" ::: "memory");\
                     SB(); } while (0)
#define VMW(n) asm volatile("s_waitcnt vmcnt(" #n ")" ::: "memory")

__global__ __launch_bounds__(512, 2) void gemm_fused(
    const unsigned short* __restrict__ Xb,   // [M][K] bf16 bits
    const unsigned short* __restrict__ Wb,   // [2048][K] bf16 bits (Wcat)
    const float* __restrict__ bz, const float* __restrict__ bh,
    unsigned int* __restrict__ ZG,           // [M][1024] packed (z | g<<16)
    float* __restrict__ Pp, float* __restrict__ Qq)   // [B][64][1024]
{
  extern __shared__ __align__(16) char smem[];   // 2 x (A 32KB + B 32KB)
  const int tid  = threadIdx.x;
  const int wave = tid >> 6;
  const int lane = tid & 63;
  const int wm = wave >> 2, wn = wave & 3;       // 2M x 4N waves
  const int fr = lane & 15, kg = lane >> 4;

  // XCD-bijective swizzle (1024 % 8 == 0); N-fastest within each XCD strip.
  int swz = (blockIdx.x & 7) * 128 + (blockIdx.x >> 3);
  const int m0 = (swz >> 3) * 256;
  const int e0 = (swz & 7) * 256;                // Wcat col-tile base

  // staging per-thread constants (pre-swizzled global source)
  const int arow = tid >> 3;                         // 0..63 row within round
  const int aslx = ((tid & 7) ^ (arow & 7)) * 8;     // swizzled 16B-chunk
  const unsigned short* pXa = Xb + (size_t)(m0 + arow) * KK_ + aslx;
  const unsigned short* pWb = Wb + (size_t)(e0 + arow) * KK_ + aslx;
  const int wofs = wave * 1024;                      // wave slice (bytes)

  // ds_read per-thread constants (swizzled read side)
  const int rA7 = (wm * 128 + fr) * 128;             // A row byte offset
  const int rB7 = 32768 + (wn * 64 + fr) * 128;      // B row byte offset
  const int fx = fr & 7;
  const int sk0 = (kg ^ fx) * 16;                    // k-half 0 slot byte
  const int sk1 = sk0 ^ 64;                          // k-half 1 slot byte

  f32x4 acc[8][4];
  #pragma unroll
  for (int i = 0; i < 8; i++)
    #pragma unroll
    for (int j = 0; j < 4; j++)
      acc[i][j] = (f32x4){0.f, 0.f, 0.f, 0.f};
  u32x4 aP[4], aQ[4], bk0[4], bk1[4];   // fragment reg sets (static idx only)

  // prologue: stage K-tile 0 into buf0; first-needed 6 rounds drained
  STA(0, smem, 0); STA(2, smem, 0); STB(0, smem, 0);
  STB(1, smem, 0); STB(2, smem, 0); STB(3, smem, 0);
  STA(1, smem, 0); STA(3, smem, 0);
  VMW(2);                                   // A0,A2,B0..B3 landed
  __builtin_amdgcn_s_barrier();
  SB();
  RD_A(aP, smem, 0, sk0);                   // (mh0,kh0) of tile 0
  RD_B(bk0, smem, sk0);

  // loop: 4 phases/tile, ONE barrier/phase, reads pipelined one phase ahead.
  // Wait ledger (per wave, outstanding <= 8 vmem / 8 ds):
  //  ph0: VMW(0) drains A1',A3' (issued ph2 prev) before reading them.
  //  ph3: VMW(2) drains A0',A2',B0'..B3' (issued ph0/ph1) before reading nb.
  //  LGKM(n) leaves the n just-issued reads outstanding, drains the set the
  //  imminent MFMA consumes (issued one phase earlier).
  #pragma unroll 1
  for (int t = 0; t < 15; ++t) {
    const char* cb = smem + ((t & 1) << 16);
    char* nb = smem + (((t + 1) & 1) << 16);
    const int kn = (t + 1) * 64;                     // half-elem K offset
    // ph0: MFMA(mh0,kh0) on aP/bk0; read aQ=(mh1,kh0); stage A0',A2',B0'
    VMW(0);
    BAR();
    RD_A(aQ, cb, 1, sk0);
    STA(0, nb, kn); STA(2, nb, kn); STB(0, nb, kn);
    LGKM(4);
    MFMA16(aP, bk0, 0);
    // ph1: MFMA(mh1,kh0) on aQ/bk0; read aP=(mh0,kh1)+bk1; stage B1'..B3'
    BAR();
    RD_A(aP, cb, 0, sk1);
    RD_B(bk1, cb, sk1);
    STB(1, nb, kn); STB(2, nb, kn); STB(3, nb, kn);
    LGKM(8);
    MFMA16(aQ, bk0, 1);
    // ph2: MFMA(mh0,kh1) on aP/bk1; read aQ=(mh1,kh1); stage A1',A3'
    BAR();
    RD_A(aQ, cb, 1, sk1);
    STA(1, nb, kn); STA(3, nb, kn);
    LGKM(4);
    MFMA16(aP, bk1, 0);
    // ph3: MFMA(mh1,kh1) on aQ/bk1; read next tile's aP+bk0 from nb
    VMW(2);
    BAR();
    RD_A(aP, nb, 0, sk0);
    RD_B(bk0, nb, sk0);
    LGKM(8);
    MFMA16(aQ, bk1, 1);
  }
  {                                                  // peeled tile 15 (buf1)
    const char* cb = smem + 65536;
    VMW(0);
    BAR();
    RD_A(aQ, cb, 1, sk0);
    LGKM(4);  MFMA16(aP, bk0, 0);
    BAR();
    RD_A(aP, cb, 0, sk1);
    RD_B(bk1, cb, sk1);
    LGKM(8);  MFMA16(aQ, bk0, 1);
    BAR();
    RD_A(aQ, cb, 1, sk1);
    LGKM(4);  MFMA16(aP, bk1, 0);
    BAR();
    LGKM(0);  MFMA16(aQ, bk1, 1);
  }
  __syncthreads();                          // all LDS reads done -> reuse smem

  // ===== epilogue: activation + in-register chunk scan + packed ZG ========
  // lane's channel (j = 0,1): d = dw0 + j*16 + fr ; k = acc[a][j], th = acc[a][j+2]
  const int dw0 = (swz & 7) * 128 + wn * 32;         // wave's 32 channels
  const int t0 = m0 & 4095;                          // t base within batch
  const int bidx = m0 >> 12;                         // batch

  float bzv[2], bhv[2];
  #pragma unroll
  for (int j = 0; j < 2; ++j) {
    bzv[j] = bz[dw0 + j * 16 + fr];
    bhv[j] = bh[dw0 + j * 16 + fr];
  }

  unsigned int* ew = (unsigned int*)(smem + wave * 9216);  // [64 t][36 dw]
  const int sub = lane & 7, rowr = lane >> 3;

  #pragma unroll
  for (int p = 0; p < 2; ++p) {                      // two 64-t chunks
    float PP[2] = {1.f, 1.f}, QQ[2] = {0.f, 0.f};
    #pragma unroll
    for (int ii = 0; ii < 4; ++ii) {                 // ascending t blocks of 16
      #pragma unroll
      for (int j = 0; j < 2; ++j) {
        float segP = 1.f, segQ = 0.f;
        #pragma unroll
        for (int r = 0; r < 4; ++r) {                // 4 consecutive t
          float kz = acc[p * 4 + ii][j][r] + bzv[j];
          float th = acc[p * 4 + ii][j + 2][r] + bhv[j];
          float z = 1.0f / (1.0f + __expf(-kz));
          float g = (th >= 0.0f) ? (th + 0.5f)
                                 : (1.0f / (1.0f + __expf(-th)));
          unsigned int pk =
              (unsigned int)__half_as_ushort(__float2half(z)) |
              ((unsigned int)__half_as_ushort(__float2half(g)) << 16);
          ew[(ii * 16 + kg * 4 + r) * 36 + j * 16 + fr] = pk;
          float aa = 1.f - z;
          segP *= aa;
          segQ = fmaf(aa, segQ, z * g);
        }
        // suffix-combine across kg (t-ordered: kg ascending = later)
        float p1 = __shfl_down(segP, 16), q1 = __shfl_down(segQ, 16);
        segQ = fmaf(p1, segQ, q1); segP *= p1;
        float p2 = __shfl_down(segP, 32), q2 = __shfl_down(segQ, 32);
        segQ = fmaf(p2, segQ, q2); segP *= p2;
        QQ[j] = fmaf(segP, QQ[j], segQ);
        PP[j] *= segP;
      }
    }
    if (kg == 0) {                                   // one lane per (d, chunk)
      const int cg = (t0 >> 6) + wm * 2 + p;
      #pragma unroll
      for (int j = 0; j < 2; ++j) {
        size_t po = ((size_t)bidx * NCH + cg) * DD_ + dw0 + j * 16 + fr;
        Pp[po] = PP[j];
        Qq[po] = QQ[j];
      }
    }
    // coalesced ZG store via LDS readback (wave-synchronous, own region)
    #pragma unroll
    for (int q = 0; q < 8; ++q) {
      int rl = q * 8 + rowr;
      uint4 v = *reinterpret_cast<const uint4*>(&ew[rl * 36 + sub * 4]);
      size_t rg = (size_t)(m0 + wm * 128 + p * 64 + rl);
      *reinterpret_cast<uint4*>(&ZG[rg * DD_ + dw0 + sub * 4]) = v;
    }
  }
}

// ---------------- scan phase B: exclusive scan over chunks ----------------
__global__ __launch_bounds__(256) void scan_combine(
    const float* __restrict__ P, const float* __restrict__ Q,
    float* __restrict__ H) {
  const int d = blockIdx.x * 256 + threadIdx.x;   // gridDim.x = 4 -> d 0..1023
  const int b = blockIdx.y;
  float h = 0.f;
  for (int c = 0; c < NCH; ++c) {
    size_t o = ((size_t)b * NCH + c) * DD_ + d;
    H[o] = h;
    h = fmaf(P[o], h, Q[o]);
  }
}

// ---------------- scan phase C: apply + write output ----------------
__global__ __launch_bounds__(256) void scan_apply(
    const uint4* __restrict__ ZG, const float4* __restrict__ H,
    float4* __restrict__ out) {
  const int d4 = threadIdx.x;
  const int c  = blockIdx.x;
  const int b  = blockIdx.y;
  float4 h = H[((size_t)b * NCH + c) * (DD_ / 4) + d4];
  size_t base = ((size_t)b * TT_ + (size_t)c * LCH) * (DD_ / 4) + d4;
  for (int t = 0; t < LCH; ++t) {
    uint4 w = ZG[base + (size_t)t * (DD_ / 4)];
    float z, g, a;
    z = __half2float(__ushort_as_half((unsigned short)(w.x & 0xffff)));
    g = __half2float(__ushort_as_half((unsigned short)(w.x >> 16)));
    a = 1.f - z; h.x = fmaf(a, h.x, z * g);
    z = __half2float(__ushort_as_half((unsigned short)(w.y & 0xffff)));
    g = __half2float(__ushort_as_half((unsigned short)(w.y >> 16)));
    a = 1.f - z; h.y = fmaf(a, h.y, z * g);
    z = __half2float(__ushort_as_half((unsigned short)(w.z & 0xffff)));
    g = __half2float(__ushort_as_half((unsigned short)(w.z >> 16)));
    a = 1.f - z; h.z = fmaf(a, h.z, z * g);
    z = __half2float(__ushort_as_half((unsigned short)(w.w & 0xffff)));
    g = __half2float(__ushort_as_half((unsigned short)(w.w >> 16)));
    a = 1.f - z; h.w = fmaf(a, h.w, z * g);
    out[base + (size_t)t * (DD_ / 4)] = h;
  }
}

extern "C" void kernel_launch(void* const* d_in, const int* in_sizes, int n_in,
                              void* d_out, int out_size, void* d_ws, size_t ws_size,
                              hipStream_t stream) {
  const float* X  = (const float*)d_in[0];  // [8,4096,1024]
  const float* Wz = (const float*)d_in[1];  // [1024,1024]
  const float* bz = (const float*)d_in[2];
  const float* Wh = (const float*)d_in[3];
  const float* bh = (const float*)d_in[4];
  float* out = (float*)d_out;

  const size_t szXb = (size_t)MM_ * DD_ * 2;      // 64 MiB  bf16 X
  const size_t szWb = (size_t)2 * DD_ * DD_ * 2;  //  4 MiB  bf16 Wcat
  const size_t szZG = (size_t)MM_ * DD_ * 4;      // 128 MiB packed z,g
  const size_t szPQ = (size_t)BB_ * NCH * DD_ * 4;//  2 MiB  each

  char* ws = (char*)d_ws;
  unsigned short *Xb, *Wb;
  const size_t needA = szXb + szWb + szZG + 3 * szPQ;
  if (ws_size >= needA) {
    Xb = (unsigned short*)ws;              ws += szXb;
    Wb = (unsigned short*)ws;              ws += szWb;
  } else {
    // fallback: stage X/W inside d_out (dead until scan_apply), rest in ws
    Xb = (unsigned short*)d_out;
    Wb = (unsigned short*)((char*)d_out + szXb);
  }
  unsigned int* ZG = (unsigned int*)ws;  ws += szZG;
  float* P = (float*)ws;  ws += szPQ;
  float* Q = (float*)ws;  ws += szPQ;
  float* H = (float*)ws;

  // 1) single merged conversion launch: X -> bf16, W -> interleaved Wcat
  cvt_inputs<<<2048, 256, 0, stream>>>((const float4*)X, (const float4*)Wz,
                                       (const float4*)Wh, (ushort4*)Xb,
                                       (ushort4*)Wb);
  // 2) fused GEMM -> packed ZG + per-chunk P,Q  (M=32768, N=2048, K=1024)
  gemm_fused<<<(MM_ / 256) * ((2 * DD_) / 256), 512, 131072, stream>>>(
      Xb, Wb, bz, bh, ZG, P, Q);

  // 3) chunk combine + apply
  scan_combine<<<dim3(4, BB_), 256, 0, stream>>>(P, Q, H);
  scan_apply<<<dim3(NCH, BB_), 256, 0, stream>>>((const uint4*)ZG,
                                                 (const float4*)H, (float4*)out);
}